// Round 4
// baseline (376.048 us; speedup 1.0000x reference)
//
#include <hip/hip_runtime.h>
#include <hip/hip_bf16.h>

typedef short short8 __attribute__((ext_vector_type(8)));
typedef short short4_t __attribute__((ext_vector_type(4)));
typedef float floatx4 __attribute__((ext_vector_type(4)));

#define DEVI __device__ __forceinline__

// Dims: B=4, T=4096, D=256, E=12 (4x k5, 4x k9, 4x k17), 16384 tokens.
// fp32 in/out; MFMA operands bf16.
// fused: 256 blocks x 1024 threads. BM=64. waves 0-7 conv producers,
// waves 8-15 GEMM consumers (n-slice 32 each). K chunked 128 (half expert),
// LDS A dbuf. Router softmax precomputed in router_kernel -> ws.
//
// ws layout (bytes):
//   projWT bf16 [12][256f][256d] @ 0          (1,572,864)
//   outWT  bf16 [256f][256k]     @ 1,572,864  (131,072)
//   projbT bf16 [256n][32k]      @ 1,703,936  (16,384)   (k>=12 zero)
//   wts    f32  [16384][12]      @ 1,720,320  (786,432)

DEVI float bf2f(__hip_bfloat16 v) { return __bfloat162float(v); }
DEVI __hip_bfloat16 f2bf(float v) { return __float2bfloat16(v); }

// ---------------------------------------------------------------- prep ----
// 209 blocks: 0..191 projW 64x64 transpose tiles, 192..207 outW, 208 projbT.
__global__ __launch_bounds__(256) void prep_kernel(
    const float* __restrict__ projW,   // [12][256d][256f]
    const float* __restrict__ outW,    // [256k][256f]
    const float* __restrict__ projb,   // [12][256]
    __hip_bfloat16* __restrict__ projWT,  // [12][256f][256d]
    __hip_bfloat16* __restrict__ outWT,   // [256f][256k]
    __hip_bfloat16* __restrict__ projbT)  // [256n][32k]
{
    __shared__ __align__(16) __hip_bfloat16 Tt[64 * 72];
    const int tid = threadIdx.x;
    const int bid = blockIdx.x;

    if (bid == 208) {
        int n = tid;
#pragma unroll
        for (int k = 0; k < 32; k++)
            projbT[n * 32 + k] = (k < 12) ? f2bf(projb[k * 256 + n]) : f2bf(0.f);
        return;
    }

    const float* src;
    __hip_bfloat16* dst;
    if (bid < 192) {
        int e = bid >> 4, ti = (bid & 15) >> 2, tj = bid & 3;
        src = projW + (e << 16) + (ti * 64) * 256 + tj * 64;
        dst = projWT + (e << 16) + (tj * 64) * 256 + ti * 64;
    } else {
        int b2 = bid - 192, ti = b2 >> 2, tj = b2 & 3;
        src = outW + (ti * 64) * 256 + tj * 64;
        dst = outWT + (tj * 64) * 256 + ti * 64;
    }
#pragma unroll
    for (int i = 0; i < 4; i++) {
        int r = i * 16 + (tid >> 4);
        int c4 = (tid & 15) * 4;
        float4 f = *(const float4*)(src + r * 256 + c4);
        Tt[(c4 + 0) * 72 + r] = f2bf(f.x);
        Tt[(c4 + 1) * 72 + r] = f2bf(f.y);
        Tt[(c4 + 2) * 72 + r] = f2bf(f.z);
        Tt[(c4 + 3) * 72 + r] = f2bf(f.w);
    }
    __syncthreads();
#pragma unroll
    for (int i = 0; i < 2; i++) {
        int c = i * 32 + (tid >> 3);
        int r8 = (tid & 7) * 8;
        *(short8*)(dst + c * 256 + r8) = *(const short8*)(Tt + c * 72 + r8);
    }
}

// -------------------------------------------------------------- router ----
// 4096 blocks x 256 thr; wave per token (4 tokens/block). wts = softmax(x@rW+rb)
__global__ __launch_bounds__(256) void router_kernel(
    const float* __restrict__ x,     // [16384][256]
    const float* __restrict__ rW,    // [256][12]
    const float* __restrict__ rb,    // [12]
    float* __restrict__ wts)         // [16384][12]
{
    const int wv = threadIdx.x >> 6, lane = threadIdx.x & 63;
    const int token = blockIdx.x * 4 + wv;
    float4 xv = *(const float4*)(x + (size_t)token * 256 + lane * 4);
    float le[12];
#pragma unroll
    for (int e = 0; e < 12; e++) le[e] = 0.f;
#pragma unroll
    for (int j = 0; j < 4; j++) {
        const float* rr = rW + (4 * lane + j) * 12;
        float xj = (j == 0) ? xv.x : (j == 1) ? xv.y : (j == 2) ? xv.z : xv.w;
#pragma unroll
        for (int e = 0; e < 12; e++) le[e] += xj * rr[e];
    }
#pragma unroll
    for (int e = 0; e < 12; e++) {
        float v = le[e];
        v += __shfl_xor(v, 1);  v += __shfl_xor(v, 2);  v += __shfl_xor(v, 4);
        v += __shfl_xor(v, 8);  v += __shfl_xor(v, 16); v += __shfl_xor(v, 32);
        le[e] = v + rb[e];
    }
    float mx = le[0];
#pragma unroll
    for (int e = 1; e < 12; e++) mx = fmaxf(mx, le[e]);
    float sm = 0.f;
#pragma unroll
    for (int e = 0; e < 12; e++) { le[e] = __expf(le[e] - mx); sm += le[e]; }
    float inv = 1.f / sm;
    float* wp = wts + (size_t)token * 12;
    if (lane == 0) { float4 o = {le[0]*inv, le[1]*inv, le[2]*inv, le[3]*inv};  *(float4*)(wp) = o; }
    if (lane == 1) { float4 o = {le[4]*inv, le[5]*inv, le[6]*inv, le[7]*inv};  *(float4*)(wp + 4) = o; }
    if (lane == 2) { float4 o = {le[8]*inv, le[9]*inv, le[10]*inv, le[11]*inv}; *(float4*)(wp + 8) = o; }
}

// --------------------------------------------------------------- fused ----
// LDS (45,056 B):
//   As     bf16 2 x [64][144] @ 0      (36,864)  A chunk dbuf (w * conv)
//   normed bf16 [64][272]     @ 0      (34,816)  aliases As after chunk loop
//   wts_s  f32  [64][12]      @ 36,864 ( 3,072)
//   psum   f32  [64][9]       @ 39,936 ( 2,304)
//   psq    f32  [64][9]       @ 42,240 ( 2,304)
//   muA    f32  [64]          @ 44,544   rsA @ 44,800

template<int K>
DEVI void conv_col(const float* __restrict__ cw,   // expert base [K][256]
                   const float* __restrict__ xb, int t0,
                   const float* __restrict__ wts_s, int e,
                   __hip_bfloat16* __restrict__ dstbuf,
                   int d_in, int d_g, int tloc)
{
    float c[K];
#pragma unroll
    for (int j = 0; j < K; j++) c[j] = cw[j * 256 + d_g];
    float w[K - 1];
#pragma unroll
    for (int i = 0; i < K - 1; i++) {
        int gt = t0 + tloc - (K - 1) + i;
        w[i] = (gt >= 0) ? xb[(size_t)gt * 256 + d_g] : 0.f;
    }
#pragma unroll
    for (int t = 0; t < 16; t++) {
        float nv = xb[(size_t)(t0 + tloc + t) * 256 + d_g];
        float s = nv * c[K - 1];
#pragma unroll
        for (int i = 0; i < K - 1; i++) s += w[i] * c[i];
        float wt = wts_s[(tloc + t) * 12 + e];
        dstbuf[(tloc + t) * 144 + d_in] = f2bf(s * wt);
#pragma unroll
        for (int i = 0; i + 1 < K - 1; i++) w[i] = w[i + 1];
        w[K - 2] = nv;
    }
}

__global__ __launch_bounds__(1024) void fused_kernel(
    const float* __restrict__ x,
    const float* __restrict__ ck5, const float* __restrict__ ck9,
    const float* __restrict__ ck17,
    const float* __restrict__ gmm, const float* __restrict__ bta,
    const float* __restrict__ outb,
    const __hip_bfloat16* __restrict__ projWT,
    const __hip_bfloat16* __restrict__ outWT,
    const __hip_bfloat16* __restrict__ projbT,
    const float* __restrict__ wts,
    float* __restrict__ out)
{
    __shared__ __align__(16) char smem[45056];
    __hip_bfloat16* As = (__hip_bfloat16*)smem;      // 2 x [64][144]
    __hip_bfloat16* normed = (__hip_bfloat16*)smem;  // [64][272] later
    float* wts_s = (float*)(smem + 36864);
    float* psum  = (float*)(smem + 39936);
    float* psq   = (float*)(smem + 42240);
    float* muA   = (float*)(smem + 44544);
    float* rsA   = (float*)(smem + 44800);

    const int tid  = threadIdx.x;
    const int wave = tid >> 6;
    const int lane = tid & 63;
    const int quad = lane >> 4;
    const int l16  = lane & 15;
    const bool prod = (wave < 8);
    const int nsl  = (wave - 8) * 32;          // consumer n-slice base
    const int m0   = blockIdx.x * 64;
    const int bb   = m0 >> 12;
    const int t0   = m0 & 4095;
    const float* xb = x + (size_t)bb * 4096 * 256;

    // stage router weights [64][12] f32
    if (tid < 192)
        ((float4*)wts_s)[tid] = ((const float4*)(wts + (size_t)m0 * 12))[tid];
    __syncthreads();

    floatx4 acc[4][2];
    if (!prod) {
#pragma unroll
        for (int i = 0; i < 4; i++)
#pragma unroll
            for (int j = 0; j < 2; j++) acc[i][j] = {0.f, 0.f, 0.f, 0.f};
    }

    // producer chunk helper: chunk c in [0,24]; 24 = bias chunk
    auto produce = [&](int c) {
        __hip_bfloat16* dst = As + (c & 1) * 9216;
        if (c == 24) {
            int t = tid >> 3, k4 = (tid & 7) * 4;
            short4_t v;
#pragma unroll
            for (int j = 0; j < 4; j++) {
                int k = k4 + j;
                __hip_bfloat16 b = (k < 12) ? f2bf(wts_s[t * 12 + k]) : f2bf(0.f);
                v[j] = *(short*)&b;
            }
            *(short4_t*)(dst + t * 144 + k4) = v;
        } else {
            int e = c >> 1, h = c & 1;
            int d_in = tid & 127, seg = tid >> 7, tloc = seg * 16;
            int d_g = h * 128 + d_in;
            if (e < 4)
                conv_col<5>(ck5 + e * 5 * 256, xb, t0, wts_s, e, dst, d_in, d_g, tloc);
            else if (e < 8)
                conv_col<9>(ck9 + (e - 4) * 9 * 256, xb, t0, wts_s, e, dst, d_in, d_g, tloc);
            else
                conv_col<17>(ck17 + (e - 8) * 17 * 256, xb, t0, wts_s, e, dst, d_in, d_g, tloc);
        }
    };

    if (prod) produce(0);
    __syncthreads();

#pragma unroll 1
    for (int c = 0; c < 25; c++) {
        if (prod) {
            if (c < 24) produce(c + 1);
        } else {
            const __hip_bfloat16* Ab = As + (c & 1) * 9216;
            if (c < 24) {
                int e = c >> 1, h = c & 1;
                const __hip_bfloat16* Bg = projWT + (e << 16) + h * 128;
#pragma unroll
                for (int ks = 0; ks < 4; ks++) {
                    const __hip_bfloat16* bp = Bg + ks * 32 + quad * 8;
                    short8 b0 = *(const short8*)(bp + (nsl + l16) * 256);
                    short8 b1 = *(const short8*)(bp + (nsl + 16 + l16) * 256);
#pragma unroll
                    for (int mf = 0; mf < 4; mf++) {
                        short8 a = *(const short8*)(Ab + (mf * 16 + l16) * 144 + ks * 32 + quad * 8);
                        acc[mf][0] = __builtin_amdgcn_mfma_f32_16x16x32_bf16(a, b0, acc[mf][0], 0, 0, 0);
                        acc[mf][1] = __builtin_amdgcn_mfma_f32_16x16x32_bf16(a, b1, acc[mf][1], 0, 0, 0);
                    }
                }
            } else {
                const __hip_bfloat16* bp = projbT + quad * 8;
                short8 b0 = *(const short8*)(bp + (nsl + l16) * 32);
                short8 b1 = *(const short8*)(bp + (nsl + 16 + l16) * 32);
#pragma unroll
                for (int mf = 0; mf < 4; mf++) {
                    short8 a = *(const short8*)(Ab + (mf * 16 + l16) * 144 + quad * 8);
                    acc[mf][0] = __builtin_amdgcn_mfma_f32_16x16x32_bf16(a, b0, acc[mf][0], 0, 0, 0);
                    acc[mf][1] = __builtin_amdgcn_mfma_f32_16x16x32_bf16(a, b1, acc[mf][1], 0, 0, 0);
                }
            }
        }
        __syncthreads();
    }

    // ---- LN stats from accumulators (exact f32) ----
    if (!prod) {
        float s[16], s2[16];
#pragma unroll
        for (int mf = 0; mf < 4; mf++)
#pragma unroll
            for (int r = 0; r < 4; r++) {
                int i = mf * 4 + r;
                float v0 = acc[mf][0][r], v1 = acc[mf][1][r];
                s[i] = v0 + v1; s2[i] = v0 * v0 + v1 * v1;
            }
#pragma unroll
        for (int m = 1; m <= 8; m <<= 1) {
#pragma unroll
            for (int i = 0; i < 16; i++) {
                s[i]  += __shfl_xor(s[i], m);
                s2[i] += __shfl_xor(s2[i], m);
            }
        }
        int cw = wave - 8;
#pragma unroll
        for (int i = 0; i < 16; i++) {
            if (l16 == i) {
                int row = (i >> 2) * 16 + quad * 4 + (i & 3);
                psum[row * 9 + cw] = s[i];
                psq[row * 9 + cw]  = s2[i];
            }
        }
    }
    __syncthreads();
    if (tid < 64) {
        float ss = 0.f, qq = 0.f;
#pragma unroll
        for (int p = 0; p < 8; p++) { ss += psum[tid * 9 + p]; qq += psq[tid * 9 + p]; }
        float mu = ss * 0.00390625f;
        float var = fmaxf(qq * 0.00390625f - mu * mu, 0.f);
        muA[tid] = mu;
        rsA[tid] = rsqrtf(var + 1e-5f);
    }
    __syncthreads();

    // ---- normalize acc -> normed bf16 [64][272] ----
    if (!prod) {
        int col0 = nsl + l16, col1 = nsl + 16 + l16;
        float g0 = gmm[col0], g1 = gmm[col1];
        float bt0 = bta[col0], bt1 = bta[col1];
#pragma unroll
        for (int mf = 0; mf < 4; mf++)
#pragma unroll
            for (int r = 0; r < 4; r++) {
                int row = mf * 16 + quad * 4 + r;
                float mu = muA[row], rs = rsA[row];
                normed[row * 272 + col0] = f2bf((acc[mf][0][r] - mu) * rs * g0 + bt0);
                normed[row * 272 + col1] = f2bf((acc[mf][1][r] - mu) * rs * g1 + bt1);
            }
    }
    __syncthreads();

    // ---- out = normed @ out_W + out_b ----
    if (!prod) {
        floatx4 acc2[4][2];
#pragma unroll
        for (int i = 0; i < 4; i++)
#pragma unroll
            for (int j = 0; j < 2; j++) acc2[i][j] = {0.f, 0.f, 0.f, 0.f};
#pragma unroll
        for (int ks = 0; ks < 8; ks++) {
            const __hip_bfloat16* bp = outWT + ks * 32 + quad * 8;
            short8 b0 = *(const short8*)(bp + (nsl + l16) * 256);
            short8 b1 = *(const short8*)(bp + (nsl + 16 + l16) * 256);
#pragma unroll
            for (int mf = 0; mf < 4; mf++) {
                short8 a = *(const short8*)(normed + (mf * 16 + l16) * 272 + ks * 32 + quad * 8);
                acc2[mf][0] = __builtin_amdgcn_mfma_f32_16x16x32_bf16(a, b0, acc2[mf][0], 0, 0, 0);
                acc2[mf][1] = __builtin_amdgcn_mfma_f32_16x16x32_bf16(a, b1, acc2[mf][1], 0, 0, 0);
            }
        }
        int col0 = nsl + l16, col1 = nsl + 16 + l16;
        float ob0 = outb[col0], ob1 = outb[col1];
        float* op = out + (size_t)m0 * 256;
#pragma unroll
        for (int mf = 0; mf < 4; mf++)
#pragma unroll
            for (int r = 0; r < 4; r++) {
                int row = mf * 16 + quad * 4 + r;
                op[row * 256 + col0] = acc2[mf][0][r] + ob0;
                op[row * 256 + col1] = acc2[mf][1][r] + ob1;
            }
    }
}

// -------------------------------------------------------------- launch ----
extern "C" void kernel_launch(void* const* d_in, const int* in_sizes, int n_in,
                              void* d_out, int out_size, void* d_ws, size_t ws_size,
                              hipStream_t stream)
{
    (void)in_sizes; (void)n_in; (void)out_size; (void)ws_size;
    const float* x     = (const float*)d_in[0];
    const float* ck5   = (const float*)d_in[1];
    const float* ck9   = (const float*)d_in[2];
    const float* ck17  = (const float*)d_in[3];
    const float* projW = (const float*)d_in[4];
    const float* projb = (const float*)d_in[5];
    const float* rW    = (const float*)d_in[6];
    const float* rb    = (const float*)d_in[7];
    const float* outW  = (const float*)d_in[8];
    const float* outb  = (const float*)d_in[9];
    const float* gmm   = (const float*)d_in[10];
    const float* bta   = (const float*)d_in[11];

    __hip_bfloat16* projWT = (__hip_bfloat16*)d_ws;
    __hip_bfloat16* outWT  = (__hip_bfloat16*)((char*)d_ws + 1572864);
    __hip_bfloat16* projbT = (__hip_bfloat16*)((char*)d_ws + 1703936);
    float*          wtsws  = (float*)((char*)d_ws + 1720320);

    prep_kernel<<<dim3(209), dim3(256), 0, stream>>>(projW, outW, projb,
                                                     projWT, outWT, projbT);
    router_kernel<<<dim3(4096), dim3(256), 0, stream>>>(x, rW, rb, wtsws);
    fused_kernel<<<dim3(256), dim3(1024), 0, stream>>>(
        x, ck5, ck9, ck17, gmm, bta, outb,
        projWT, outWT, projbT, wtsws, (float*)d_out);
}

// Round 5
// 368.220 us; speedup vs baseline: 1.0213x; 1.0213x over previous
//
#include <hip/hip_runtime.h>
#include <hip/hip_bf16.h>

typedef short short8 __attribute__((ext_vector_type(8)));
typedef short short4_t __attribute__((ext_vector_type(4)));
typedef float floatx4 __attribute__((ext_vector_type(4)));

#define DEVI __device__ __forceinline__

// Dims: B=4, T=4096, D=256, E=12 (4x k5, 4x k9, 4x k17), 16384 tokens.
// fp32 in/out; MFMA operands bf16.
//
// prep:  4305 blocks x 256: b<4096 -> x->bf16 convert + router softmax;
//        b>=4096 -> weight transposes (192 projW + 16 outW + 1 projbT).
// fused: 256 blocks x 768 (12 waves): waves 0-7 conv producers, 8-11 GEMM
//        consumers (n-slice 64). BM=64. Chunk = half-expert (128 k), single
//        rotating A buffer with 2 slots, 1 barrier/chunk. proj_b folded in
//        as a 25th MFMA chunk (A=router wts). LN stats from accumulators.
//
// ws layout (bytes):
//   projWT bf16 [12][256f][256d] @ 0          (1,572,864)
//   outWT  bf16 [256f][256k]     @ 1,572,864  (131,072)
//   projbT bf16 [256n][32k]      @ 1,703,936  (16,384)   (k>=12 zero)
//   wts    f32  [16384][12]      @ 1,720,320  (786,432)
//   xbf    bf16 [16384][256]     @ 2,506,752  (8,388,608)

DEVI float bf2f(__hip_bfloat16 v) { return __bfloat162float(v); }
DEVI __hip_bfloat16 f2bf(float v) { return __float2bfloat16(v); }
DEVI unsigned short bfbits(float v) { __hip_bfloat16 b = f2bf(v); return *(unsigned short*)&b; }
DEVI float lo_of(unsigned int u) { unsigned int t = u << 16; return *(float*)&t; }
DEVI float hi_of(unsigned int u) { unsigned int t = u & 0xffff0000u; return *(float*)&t; }

// ---------------------------------------------------------------- prep ----
__global__ __launch_bounds__(256) void prep_kernel(
    const float* __restrict__ x,       // [16384][256]
    const float* __restrict__ rW,      // [256][12]
    const float* __restrict__ rb,      // [12]
    const float* __restrict__ projW,   // [12][256d][256f]
    const float* __restrict__ outW,    // [256k][256f]
    const float* __restrict__ projb,   // [12][256]
    __hip_bfloat16* __restrict__ xbf,     // [16384][256]
    float* __restrict__ wts,              // [16384][12]
    __hip_bfloat16* __restrict__ projWT,  // [12][256f][256d]
    __hip_bfloat16* __restrict__ outWT,   // [256f][256k]
    __hip_bfloat16* __restrict__ projbT)  // [256n][32k]
{
    const int bid = blockIdx.x;
    const int tid = threadIdx.x;

    if (bid < 4096) {
        // ---- x convert + router: wave per token, 4 tokens/block ----
        const int wv = tid >> 6, lane = tid & 63;
        const int token = bid * 4 + wv;
        float4 xv = *(const float4*)(x + (size_t)token * 256 + lane * 4);
        short4_t pk;
        pk[0] = (short)bfbits(xv.x); pk[1] = (short)bfbits(xv.y);
        pk[2] = (short)bfbits(xv.z); pk[3] = (short)bfbits(xv.w);
        *(short4_t*)(xbf + (size_t)token * 256 + lane * 4) = pk;

        float le[12];
#pragma unroll
        for (int e = 0; e < 12; e++) le[e] = 0.f;
#pragma unroll
        for (int j = 0; j < 4; j++) {
            const float* rr = rW + (4 * lane + j) * 12;
            float xj = (j == 0) ? xv.x : (j == 1) ? xv.y : (j == 2) ? xv.z : xv.w;
#pragma unroll
            for (int e = 0; e < 12; e++) le[e] += xj * rr[e];
        }
#pragma unroll
        for (int e = 0; e < 12; e++) {
            float v = le[e];
            v += __shfl_xor(v, 1);  v += __shfl_xor(v, 2);  v += __shfl_xor(v, 4);
            v += __shfl_xor(v, 8);  v += __shfl_xor(v, 16); v += __shfl_xor(v, 32);
            le[e] = v + rb[e];
        }
        float mx = le[0];
#pragma unroll
        for (int e = 1; e < 12; e++) mx = fmaxf(mx, le[e]);
        float sm = 0.f;
#pragma unroll
        for (int e = 0; e < 12; e++) { le[e] = __expf(le[e] - mx); sm += le[e]; }
        float inv = 1.f / sm;
        float* wp = wts + (size_t)token * 12;
        if (lane == 0) { float4 o = {le[0]*inv, le[1]*inv, le[2]*inv,  le[3]*inv};  *(float4*)(wp) = o; }
        if (lane == 1) { float4 o = {le[4]*inv, le[5]*inv, le[6]*inv,  le[7]*inv};  *(float4*)(wp + 4) = o; }
        if (lane == 2) { float4 o = {le[8]*inv, le[9]*inv, le[10]*inv, le[11]*inv}; *(float4*)(wp + 8) = o; }
        return;
    }

    // ---- weight transposes ----
    __shared__ __align__(16) __hip_bfloat16 Tt[64 * 72];
    const int b2 = bid - 4096;
    if (b2 == 208) {
        int n = tid;
#pragma unroll
        for (int k = 0; k < 32; k++)
            projbT[n * 32 + k] = (k < 12) ? f2bf(projb[k * 256 + n]) : f2bf(0.f);
        return;
    }
    const float* src;
    __hip_bfloat16* dst;
    if (b2 < 192) {
        int e = b2 >> 4, ti = (b2 & 15) >> 2, tj = b2 & 3;
        src = projW + (e << 16) + (ti * 64) * 256 + tj * 64;
        dst = projWT + (e << 16) + (tj * 64) * 256 + ti * 64;
    } else {
        int b3 = b2 - 192, ti = b3 >> 2, tj = b3 & 3;
        src = outW + (ti * 64) * 256 + tj * 64;
        dst = outWT + (tj * 64) * 256 + ti * 64;
    }
#pragma unroll
    for (int i = 0; i < 4; i++) {
        int r = i * 16 + (tid >> 4);
        int c4 = (tid & 15) * 4;
        float4 f = *(const float4*)(src + r * 256 + c4);
        Tt[(c4 + 0) * 72 + r] = f2bf(f.x);
        Tt[(c4 + 1) * 72 + r] = f2bf(f.y);
        Tt[(c4 + 2) * 72 + r] = f2bf(f.z);
        Tt[(c4 + 3) * 72 + r] = f2bf(f.w);
    }
    __syncthreads();
#pragma unroll
    for (int i = 0; i < 2; i++) {
        int c = i * 32 + (tid >> 3);
        int r8 = (tid & 7) * 8;
        *(short8*)(dst + c * 256 + r8) = *(const short8*)(Tt + c * 72 + r8);
    }
}

// --------------------------------------------------------------- fused ----
// LDS (40,960 B):
//   As     bf16 2 x [64][136] @ 0      (34,816)  rotating A slots (128k + 8 pad)
//   normed bf16 [64][264]     @ 0      (33,792)  aliases As after chunk loop
//   wts_s  f32  [64][12]      @ 34,816 ( 3,072)
//   psum   f32  [64][5]       @ 37,888 ( 1,280)
//   psq    f32  [64][5]       @ 39,168 ( 1,280)
//   muA    f32  [64]          @ 40,448   rsA f32 [64] @ 40,704

template<int K>
DEVI void conv_pair(const float* __restrict__ cw,     // [K][256] this expert
                    const __hip_bfloat16* __restrict__ xrow,  // batch base
                    int t0, int tloc,
                    const float* __restrict__ wts_s, int e,
                    __hip_bfloat16* __restrict__ dst, int d_l, int d_g)
{
    float c0[K], c1[K];
#pragma unroll
    for (int j = 0; j < K; j++) {
        float2 f = *(const float2*)(cw + j * 256 + d_g);
        c0[j] = f.x; c1[j] = f.y;
    }
    float w0[K - 1], w1[K - 1];
#pragma unroll
    for (int i = 0; i < K - 1; i++) {
        int tt = t0 + tloc - (K - 1) + i;
        unsigned int u = (tt >= 0) ?
            *(const unsigned int*)(xrow + (size_t)tt * 256 + d_g) : 0u;
        w0[i] = lo_of(u); w1[i] = hi_of(u);
    }
#pragma unroll
    for (int t = 0; t < 8; t++) {
        unsigned int u = *(const unsigned int*)(xrow + (size_t)(t0 + tloc + t) * 256 + d_g);
        float nv0 = lo_of(u), nv1 = hi_of(u);
        float s0 = nv0 * c0[K - 1], s1 = nv1 * c1[K - 1];
#pragma unroll
        for (int i = 0; i < K - 1; i++) { s0 += w0[i] * c0[i]; s1 += w1[i] * c1[i]; }
        float wt = wts_s[(tloc + t) * 12 + e];
        unsigned int pk = (unsigned int)bfbits(s0 * wt) |
                          ((unsigned int)bfbits(s1 * wt) << 16);
        *(unsigned int*)(dst + (tloc + t) * 136 + d_l) = pk;
#pragma unroll
        for (int i = 0; i + 1 < K - 1; i++) { w0[i] = w0[i + 1]; w1[i] = w1[i + 1]; }
        w0[K - 2] = nv0; w1[K - 2] = nv1;
    }
}

__global__ __launch_bounds__(768, 3) void fused_kernel(
    const __hip_bfloat16* __restrict__ xbf,
    const float* __restrict__ ck5, const float* __restrict__ ck9,
    const float* __restrict__ ck17,
    const float* __restrict__ gmm, const float* __restrict__ bta,
    const float* __restrict__ outb,
    const __hip_bfloat16* __restrict__ projWT,
    const __hip_bfloat16* __restrict__ outWT,
    const __hip_bfloat16* __restrict__ projbT,
    const float* __restrict__ wts,
    float* __restrict__ out)
{
    __shared__ __align__(16) char smem[40960];
    __hip_bfloat16* As = (__hip_bfloat16*)smem;       // 2 x [64][136]
    __hip_bfloat16* normed = (__hip_bfloat16*)smem;   // [64][264] later
    float* wts_s = (float*)(smem + 34816);
    float* psum  = (float*)(smem + 37888);
    float* psq   = (float*)(smem + 39168);
    float* muA   = (float*)(smem + 40448);
    float* rsA   = (float*)(smem + 40704);

    const int tid  = threadIdx.x;
    const int wave = tid >> 6;
    const int lane = tid & 63;
    const int quad = lane >> 4;
    const int l16  = lane & 15;
    const bool prod = (wave < 8);
    const int nsl  = (wave - 8) * 64;          // consumer n-slice base
    // XCD-contiguous swizzle: XCD k (blockIdx%8) gets tiles k*32..k*32+31
    const int tile = (blockIdx.x & 7) * 32 + (blockIdx.x >> 3);
    const int m0   = tile * 64;
    const int bb   = m0 >> 12;
    const int t0   = m0 & 4095;
    const __hip_bfloat16* xrow = xbf + (size_t)bb * 4096 * 256;

    if (tid < 192)
        ((float4*)wts_s)[tid] = ((const float4*)(wts + (size_t)m0 * 12))[tid];
    __syncthreads();

    // producer chunk: c in [0,24]; c<24: e=c>>1, h=c&1; c==24: bias chunk
    auto produce = [&](int c) {
        __hip_bfloat16* dst = As + (c & 1) * (64 * 136);
        if (c == 24) {
            int t = tid >> 3, k4 = (tid & 7) * 4;
            short4_t v;
#pragma unroll
            for (int j = 0; j < 4; j++) {
                int k = k4 + j;
                v[j] = (k < 12) ? (short)bfbits(wts_s[t * 12 + k]) : (short)0;
            }
            *(short4_t*)(dst + t * 136 + k4) = v;
        } else {
            int e = c >> 1, h = c & 1;
            int p = tid & 63, seg = (tid >> 6) & 7;
            int tloc = seg * 8, d_l = 2 * p, d_g = h * 128 + d_l;
            if (e < 4)
                conv_pair<5>(ck5 + e * 5 * 256, xrow, t0, tloc, wts_s, e, dst, d_l, d_g);
            else if (e < 8)
                conv_pair<9>(ck9 + (e - 4) * 9 * 256, xrow, t0, tloc, wts_s, e, dst, d_l, d_g);
            else
                conv_pair<17>(ck17 + (e - 8) * 17 * 256, xrow, t0, tloc, wts_s, e, dst, d_l, d_g);
        }
    };

    floatx4 acc[4][4];
    if (!prod) {
#pragma unroll
        for (int i = 0; i < 4; i++)
#pragma unroll
            for (int j = 0; j < 4; j++) acc[i][j] = {0.f, 0.f, 0.f, 0.f};
    }

    if (prod) produce(0);
    __syncthreads();

#pragma unroll 1
    for (int c = 0; c < 25; c++) {
        if (prod) {
            if (c < 24) produce(c + 1);
        } else {
            const __hip_bfloat16* Ar = As + (c & 1) * (64 * 136);
            if (c < 24) {
                int e = c >> 1, h = c & 1;
                const __hip_bfloat16* Bb = projWT + (e << 16) + h * 128;
                short8 br[4][4];
#pragma unroll
                for (int nt = 0; nt < 4; nt++)
#pragma unroll
                    for (int ks = 0; ks < 4; ks++)
                        br[nt][ks] = *(const short8*)(Bb + (nsl + nt * 16 + l16) * 256
                                                      + ks * 32 + quad * 8);
#pragma unroll
                for (int ks = 0; ks < 4; ks++)
#pragma unroll
                    for (int mf = 0; mf < 4; mf++) {
                        short8 a = *(const short8*)(Ar + (mf * 16 + l16) * 136
                                                    + ks * 32 + quad * 8);
#pragma unroll
                        for (int nt = 0; nt < 4; nt++)
                            acc[mf][nt] = __builtin_amdgcn_mfma_f32_16x16x32_bf16(
                                a, br[nt][ks], acc[mf][nt], 0, 0, 0);
                    }
            } else {  // bias chunk (slot 0), K=32 single step
                short8 brb[4];
#pragma unroll
                for (int nt = 0; nt < 4; nt++)
                    brb[nt] = *(const short8*)(projbT + (nsl + nt * 16 + l16) * 32 + quad * 8);
#pragma unroll
                for (int mf = 0; mf < 4; mf++) {
                    short8 a = *(const short8*)(Ar + (mf * 16 + l16) * 136 + quad * 8);
#pragma unroll
                    for (int nt = 0; nt < 4; nt++)
                        acc[mf][nt] = __builtin_amdgcn_mfma_f32_16x16x32_bf16(
                            a, brb[nt], acc[mf][nt], 0, 0, 0);
                }
            }
        }
        __syncthreads();
    }

    // ---- LN stats from accumulators (exact fp32, shuffle over l16) ----
    if (!prod) {
        float s[16], s2[16];
#pragma unroll
        for (int mf = 0; mf < 4; mf++)
#pragma unroll
            for (int r = 0; r < 4; r++) {
                int i = mf * 4 + r;
                float v = 0.f, q = 0.f;
#pragma unroll
                for (int nt = 0; nt < 4; nt++) {
                    float a = acc[mf][nt][r];
                    v += a; q += a * a;
                }
                s[i] = v; s2[i] = q;
            }
#pragma unroll
        for (int m = 1; m <= 8; m <<= 1)
#pragma unroll
            for (int i = 0; i < 16; i++) {
                s[i]  += __shfl_xor(s[i], m);
                s2[i] += __shfl_xor(s2[i], m);
            }
        int cwv = wave - 8;
#pragma unroll
        for (int i = 0; i < 16; i++)
            if (l16 == i) {
                int row = (i >> 2) * 16 + quad * 4 + (i & 3);
                psum[row * 5 + cwv] = s[i];
                psq[row * 5 + cwv]  = s2[i];
            }
    }
    __syncthreads();
    if (tid < 64) {
        float ss = 0.f, qq = 0.f;
#pragma unroll
        for (int p = 0; p < 4; p++) { ss += psum[tid * 5 + p]; qq += psq[tid * 5 + p]; }
        float mu = ss * 0.00390625f;
        float var = fmaxf(qq * 0.00390625f - mu * mu, 0.f);
        muA[tid] = mu;
        rsA[tid] = rsqrtf(var + 1e-5f);
    }
    __syncthreads();

    // ---- normalize acc -> normed bf16 [64][264] (consumers) ----
    if (!prod) {
#pragma unroll
        for (int nt = 0; nt < 4; nt++) {
            int col = nsl + nt * 16 + l16;
            float g = gmm[col], bt = bta[col];
#pragma unroll
            for (int mf = 0; mf < 4; mf++)
#pragma unroll
                for (int r = 0; r < 4; r++) {
                    int row = mf * 16 + quad * 4 + r;
                    normed[row * 264 + col] =
                        f2bf((acc[mf][nt][r] - muA[row]) * rsA[row] * g + bt);
                }
        }
    }
    __syncthreads();

    // ---- out = normed @ out_W + out_b (consumers) ----
    if (!prod) {
        floatx4 acc2[4][4];
#pragma unroll
        for (int i = 0; i < 4; i++)
#pragma unroll
            for (int j = 0; j < 4; j++) acc2[i][j] = {0.f, 0.f, 0.f, 0.f};
#pragma unroll
        for (int half = 0; half < 2; half++) {
            short8 br[4][4];
#pragma unroll
            for (int nt = 0; nt < 4; nt++)
#pragma unroll
                for (int ks = 0; ks < 4; ks++)
                    br[nt][ks] = *(const short8*)(outWT + (nsl + nt * 16 + l16) * 256
                                                  + (half * 4 + ks) * 32 + quad * 8);
#pragma unroll
            for (int ks = 0; ks < 4; ks++)
#pragma unroll
                for (int mf = 0; mf < 4; mf++) {
                    short8 a = *(const short8*)(normed + (mf * 16 + l16) * 264
                                                + (half * 4 + ks) * 32 + quad * 8);
#pragma unroll
                    for (int nt = 0; nt < 4; nt++)
                        acc2[mf][nt] = __builtin_amdgcn_mfma_f32_16x16x32_bf16(
                            a, br[nt][ks], acc2[mf][nt], 0, 0, 0);
                }
        }
        float* op = out + (size_t)m0 * 256;
#pragma unroll
        for (int nt = 0; nt < 4; nt++) {
            int col = nsl + nt * 16 + l16;
            float ob = outb[col];
#pragma unroll
            for (int mf = 0; mf < 4; mf++)
#pragma unroll
                for (int r = 0; r < 4; r++) {
                    int row = mf * 16 + quad * 4 + r;
                    op[row * 256 + col] = acc2[mf][nt][r] + ob;
                }
        }
    }
}

// -------------------------------------------------------------- launch ----
extern "C" void kernel_launch(void* const* d_in, const int* in_sizes, int n_in,
                              void* d_out, int out_size, void* d_ws, size_t ws_size,
                              hipStream_t stream)
{
    (void)in_sizes; (void)n_in; (void)out_size; (void)ws_size;
    const float* x     = (const float*)d_in[0];
    const float* ck5   = (const float*)d_in[1];
    const float* ck9   = (const float*)d_in[2];
    const float* ck17  = (const float*)d_in[3];
    const float* projW = (const float*)d_in[4];
    const float* projb = (const float*)d_in[5];
    const float* rW    = (const float*)d_in[6];
    const float* rb    = (const float*)d_in[7];
    const float* outW  = (const float*)d_in[8];
    const float* outb  = (const float*)d_in[9];
    const float* gmm   = (const float*)d_in[10];
    const float* bta   = (const float*)d_in[11];

    __hip_bfloat16* projWT = (__hip_bfloat16*)d_ws;
    __hip_bfloat16* outWT  = (__hip_bfloat16*)((char*)d_ws + 1572864);
    __hip_bfloat16* projbT = (__hip_bfloat16*)((char*)d_ws + 1703936);
    float*          wtsws  = (float*)((char*)d_ws + 1720320);
    __hip_bfloat16* xbf    = (__hip_bfloat16*)((char*)d_ws + 2506752);

    prep_kernel<<<dim3(4305), dim3(256), 0, stream>>>(
        x, rW, rb, projW, outW, projb, xbf, wtsws, projWT, outWT, projbT);
    fused_kernel<<<dim3(256), dim3(768), 0, stream>>>(
        xbf, ck5, ck9, ck17, gmm, bta, outb,
        projWT, outWT, projbT, wtsws, (float*)d_out);
}